// Round 1
// baseline (1620.707 us; speedup 1.0000x reference)
//
#include <hip/hip_runtime.h>

// GCN forward: 3x GCNConv (symmetric norm, self-loops) + mean-pool + MLP head.
// N=100000 nodes, E=3200000 edges, widths 128->16->32->64, 1024 graphs, 2 classes.

__global__ void k_fill(float* __restrict__ p, float v, int n) {
    int i = blockIdx.x * blockDim.x + threadIdx.x;
    if (i < n) p[i] = v;
}

__global__ void k_count_deg(const int* __restrict__ dst, float* __restrict__ deg, int nE) {
    int e = blockIdx.x * blockDim.x + threadIdx.x;
    if (e < nE) atomicAdd(&deg[dst[e]], 1.0f);
}

__global__ void k_dinv(float* __restrict__ deg, int n) {
    int i = blockIdx.x * blockDim.x + threadIdx.x;
    if (i < n) {
        float d = deg[i];
        deg[i] = (d > 0.0f) ? rsqrtf(d) : 0.0f;
    }
}

__global__ void k_norm(const int* __restrict__ src, const int* __restrict__ dst,
                       const float* __restrict__ dinv, float* __restrict__ norm, int nE) {
    int e = blockIdx.x * blockDim.x + threadIdx.x;
    if (e < nE) norm[e] = dinv[src[e]] * dinv[dst[e]];
}

// T[i][f] = sum_k H[i][k] * W[k][f]   (W staged in LDS; K*F <= 8192 floats)
__global__ void k_matmul(const float* __restrict__ H, const float* __restrict__ W,
                         float* __restrict__ T, int n, int K, int F) {
    extern __shared__ float sW[];
    for (int t = threadIdx.x; t < K * F; t += blockDim.x) sW[t] = W[t];
    __syncthreads();
    int idx = blockIdx.x * blockDim.x + threadIdx.x;
    int i = idx / F, f = idx - i * F;
    if (i < n) {
        const float* h = H + (long long)i * K;
        float acc = 0.0f;
        #pragma unroll 8
        for (int k = 0; k < K; ++k) acc += h[k] * sW[k * F + f];
        T[(long long)i * F + f] = acc;
    }
}

// out[i][f] = dinv[i]^2 * T[i][f]  (self-loop term; also initializes out)
__global__ void k_selfloop(const float* __restrict__ T, const float* __restrict__ dinv,
                           float* __restrict__ out, int n, int Fshift) {
    int idx = blockIdx.x * blockDim.x + threadIdx.x;
    int i = idx >> Fshift;
    if (i < n) {
        float d = dinv[i];
        out[idx] = d * d * T[idx];
    }
}

// out[dst[e]][f] += norm[e] * T[src[e]][f]
__global__ void k_scatter(const int* __restrict__ src, const int* __restrict__ dst,
                          const float* __restrict__ norm, const float* __restrict__ T,
                          float* __restrict__ out, int nE, int Fshift) {
    int idx = blockIdx.x * blockDim.x + threadIdx.x;
    int e = idx >> Fshift;
    int f = idx & ((1 << Fshift) - 1);
    if (e < nE) {
        int s = src[e], d = dst[e];
        atomicAdd(&out[(d << Fshift) + f], norm[e] * T[(s << Fshift) + f]);
    }
}

__global__ void k_bias_relu(float* __restrict__ h, const float* __restrict__ b,
                            int n, int Fshift) {
    int idx = blockIdx.x * blockDim.x + threadIdx.x;
    int i = idx >> Fshift;
    int f = idx & ((1 << Fshift) - 1);
    if (i < n) h[idx] = fmaxf(h[idx] + b[f], 0.0f);
}

// pooled[g][f] += h3[i][f]; cnt[g] += 1 (once per node)
__global__ void k_pool(const float* __restrict__ h3, const int* __restrict__ batch,
                       float* __restrict__ pooled, float* __restrict__ cnt, int n) {
    int idx = blockIdx.x * blockDim.x + threadIdx.x;
    int i = idx >> 6, f = idx & 63;
    if (i < n) {
        int g = batch[i];
        atomicAdd(&pooled[g * 64 + f], h3[i * 64 + f]);
        if (f == 0) atomicAdd(&cnt[g], 1.0f);
    }
}

// one block (64 threads) per graph: mean -> relu(mean@Wl1+bl1) -> @Wl2+bl2
__global__ void k_head(const float* __restrict__ pooled, const float* __restrict__ cnt,
                       const float* __restrict__ Wl1, const float* __restrict__ bl1,
                       const float* __restrict__ Wl2, const float* __restrict__ bl2,
                       float* __restrict__ out) {
    int g = blockIdx.x;
    int t = threadIdx.x;  // 0..63
    __shared__ float mean[64];
    __shared__ float hid[64];
    float c = fmaxf(cnt[g], 1.0f);
    mean[t] = pooled[g * 64 + t] / c;
    __syncthreads();
    float acc = bl1[t];
    #pragma unroll 8
    for (int k = 0; k < 64; ++k) acc += mean[k] * Wl1[k * 64 + t];
    hid[t] = fmaxf(acc, 0.0f);
    __syncthreads();
    if (t < 2) {
        float o = bl2[t];
        #pragma unroll 8
        for (int k = 0; k < 64; ++k) o += hid[k] * Wl2[k * 2 + t];
        out[g * 2 + t] = o;
    }
}

extern "C" void kernel_launch(void* const* d_in, const int* in_sizes, int n_in,
                              void* d_out, int out_size, void* d_ws, size_t ws_size,
                              hipStream_t stream) {
    const float* x    = (const float*)d_in[0];
    const int*   ei   = (const int*)d_in[1];
    const int*   batch= (const int*)d_in[2];
    const float* W1   = (const float*)d_in[3];
    const float* b1   = (const float*)d_in[4];
    const float* W2   = (const float*)d_in[5];
    const float* b2   = (const float*)d_in[6];
    const float* W3   = (const float*)d_in[7];
    const float* b3   = (const float*)d_in[8];
    const float* Wl1  = (const float*)d_in[9];
    const float* bl1  = (const float*)d_in[10];
    const float* Wl2  = (const float*)d_in[11];
    const float* bl2  = (const float*)d_in[12];
    float* out = (float*)d_out;

    const int n  = in_sizes[2];      // 100000 (batch vector length)
    const int nE = in_sizes[1] / 2;  // 3200000
    const int* src = ei;
    const int* dst = ei + nE;

    float* ws = (float*)d_ws;
    float* dinv   = ws;  ws += n;
    float* norm   = ws;  ws += nE;
    float* tmp    = ws;  ws += (size_t)n * 64;
    float* h1     = ws;  ws += (size_t)n * 16;
    float* h2     = ws;  ws += (size_t)n * 32;
    float* h3     = ws;  ws += (size_t)n * 64;
    float* pooled = ws;  ws += 1024 * 64;   // cnt follows contiguously
    float* cnt    = ws;  ws += 1024;

    const int B = 256;

    // ---- GCN normalization: deg -> dinv -> per-edge norm (reused by all layers)
    k_fill<<<(n + B - 1) / B, B, 0, stream>>>(dinv, 1.0f, n);  // self-loop counts as 1
    k_count_deg<<<(nE + B - 1) / B, B, 0, stream>>>(dst, dinv, nE);
    k_dinv<<<(n + B - 1) / B, B, 0, stream>>>(dinv, n);
    k_norm<<<(nE + B - 1) / B, B, 0, stream>>>(src, dst, dinv, norm, nE);

    // ---- one GCN layer
    auto layer = [&](const float* hin, int K, int F, int Fs,
                     const float* W, const float* b, float* hout) {
        int tot = n * F;
        k_matmul<<<(tot + B - 1) / B, B, (size_t)K * F * 4, stream>>>(hin, W, tmp, n, K, F);
        k_selfloop<<<(tot + B - 1) / B, B, 0, stream>>>(tmp, dinv, hout, n, Fs);
        long long etot = (long long)nE * F;
        int eblocks = (int)((etot + B - 1) / B);
        k_scatter<<<eblocks, B, 0, stream>>>(src, dst, norm, tmp, hout, nE, Fs);
        k_bias_relu<<<(tot + B - 1) / B, B, 0, stream>>>(hout, b, n, Fs);
    };

    layer(x,  128, 16, 4, W1, b1, h1);
    layer(h1,  16, 32, 5, W2, b2, h2);
    layer(h2,  32, 64, 6, W3, b3, h3);

    // ---- global mean pool + MLP head
    k_fill<<<(1024 * 64 + 1024 + B - 1) / B, B, 0, stream>>>(pooled, 0.0f, 1024 * 64 + 1024);
    k_pool<<<((n * 64) + B - 1) / B, B, 0, stream>>>(h3, batch, pooled, cnt, n);
    k_head<<<1024, 64, 0, stream>>>(pooled, cnt, Wl1, bl1, Wl2, bl2, out);
}

// Round 2
// 878.296 us; speedup vs baseline: 1.8453x; 1.8453x over previous
//
#include <hip/hip_runtime.h>

// GCN forward: 3x GCNConv (symmetric norm, self-loops) + mean-pool + MLP head.
// R2: scatter -> CSR gather; aggregate at input width via Agg(HW) = Agg(H)W.

__global__ void k_fill_f(float* __restrict__ p, float v, int n) {
    int i = blockIdx.x * blockDim.x + threadIdx.x;
    if (i < n) p[i] = v;
}

__global__ void k_fill_i(int* __restrict__ p, int v, int n) {
    int i = blockIdx.x * blockDim.x + threadIdx.x;
    if (i < n) p[i] = v;
}

__global__ void k_count_deg(const int* __restrict__ dst, int* __restrict__ ideg, int nE) {
    int e = blockIdx.x * blockDim.x + threadIdx.x;
    if (e < nE) atomicAdd(&ideg[dst[e]], 1);
}

// dinv = rsqrt(ideg+1) ; allocate a contiguous CSR slab per node
__global__ void k_alloc(const int* __restrict__ ideg, float* __restrict__ dinv,
                        int* __restrict__ start, int* __restrict__ cursor,
                        int* __restrict__ gcount, int n) {
    int i = blockIdx.x * blockDim.x + threadIdx.x;
    if (i < n) {
        dinv[i] = rsqrtf((float)(ideg[i] + 1));
        int st = atomicAdd(gcount, ideg[i]);
        start[i] = st;
        cursor[i] = st;
    }
}

// CSR fill: col[pos]=src, val[pos]=dinv[src]*dinv[dst]
__global__ void k_csr_fill(const int* __restrict__ src, const int* __restrict__ dst,
                           const float* __restrict__ dinv, int* __restrict__ cursor,
                           int* __restrict__ col, float* __restrict__ val, int nE) {
    int e = blockIdx.x * blockDim.x + threadIdx.x;
    if (e < nE) {
        int s = src[e], d = dst[e];
        int pos = atomicAdd(&cursor[d], 1);
        col[pos] = s;
        val[pos] = dinv[s] * dinv[d];
    }
}

// out[i][f] = (opt relu+bias)( dinv[i]^2*T[i][f] + sum_e val[e]*T[col[e]][f] )
template <int F, bool BR>
__global__ void k_agg(const float* __restrict__ T, const int* __restrict__ start,
                      const int* __restrict__ cnt, const int* __restrict__ col,
                      const float* __restrict__ val, const float* __restrict__ dinv,
                      const float* __restrict__ bias, float* __restrict__ out, int n) {
    int idx = blockIdx.x * blockDim.x + threadIdx.x;
    int i = idx / F;
    int f = idx % F;
    if (i >= n) return;
    int base = start[i], c = cnt[i];
    float d = dinv[i];
    float acc = d * d * T[(size_t)i * F + f];
    int k = 0;
    for (; k + 4 <= c; k += 4) {
        int s0 = col[base + k], s1 = col[base + k + 1];
        int s2 = col[base + k + 2], s3 = col[base + k + 3];
        float w0 = val[base + k], w1 = val[base + k + 1];
        float w2 = val[base + k + 2], w3 = val[base + k + 3];
        acc += w0 * T[(size_t)s0 * F + f];
        acc += w1 * T[(size_t)s1 * F + f];
        acc += w2 * T[(size_t)s2 * F + f];
        acc += w3 * T[(size_t)s3 * F + f];
    }
    for (; k < c; ++k) {
        acc += val[base + k] * T[(size_t)col[base + k] * F + f];
    }
    if (BR) acc = fmaxf(acc + bias[f], 0.0f);
    out[(size_t)i * F + f] = acc;
}

// out[i][f] = (opt relu)( sum_k H[i][k]*W[k][f] + b[f] )
template <int K, int F, bool BR>
__global__ void k_mm(const float* __restrict__ H, const float* __restrict__ W,
                     const float* __restrict__ b, float* __restrict__ out, int n) {
    __shared__ float sW[K * F];
    for (int t = threadIdx.x; t < K * F; t += blockDim.x) sW[t] = W[t];
    __syncthreads();
    int idx = blockIdx.x * blockDim.x + threadIdx.x;
    int i = idx / F, f = idx % F;
    if (i >= n) return;
    const float* h = H + (size_t)i * K;
    float acc = BR ? b[f] : 0.0f;
    #pragma unroll 8
    for (int k = 0; k < K; ++k) acc += h[k] * sW[k * F + f];
    if (BR) acc = fmaxf(acc, 0.0f);
    out[(size_t)i * F + f] = acc;
}

// pooled[g][f] += h3[i][f]; gcnt[g] += 1 (once per node)
__global__ void k_pool(const float* __restrict__ h3, const int* __restrict__ batch,
                       float* __restrict__ pooled, float* __restrict__ gcnt, int n) {
    int idx = blockIdx.x * blockDim.x + threadIdx.x;
    int i = idx >> 6, f = idx & 63;
    if (i < n) {
        int g = batch[i];
        atomicAdd(&pooled[g * 64 + f], h3[(size_t)i * 64 + f]);
        if (f == 0) atomicAdd(&gcnt[g], 1.0f);
    }
}

// one block (64 threads) per graph: mean -> relu(mean@Wl1+bl1) -> @Wl2+bl2
__global__ void k_head(const float* __restrict__ pooled, const float* __restrict__ gcnt,
                       const float* __restrict__ Wl1, const float* __restrict__ bl1,
                       const float* __restrict__ Wl2, const float* __restrict__ bl2,
                       float* __restrict__ out) {
    int g = blockIdx.x;
    int t = threadIdx.x;  // 0..63
    __shared__ float mean[64];
    __shared__ float hid[64];
    float c = fmaxf(gcnt[g], 1.0f);
    mean[t] = pooled[g * 64 + t] / c;
    __syncthreads();
    float acc = bl1[t];
    #pragma unroll 8
    for (int k = 0; k < 64; ++k) acc += mean[k] * Wl1[k * 64 + t];
    hid[t] = fmaxf(acc, 0.0f);
    __syncthreads();
    if (t < 2) {
        float o = bl2[t];
        #pragma unroll 8
        for (int k = 0; k < 64; ++k) o += hid[k] * Wl2[k * 2 + t];
        out[g * 2 + t] = o;
    }
}

extern "C" void kernel_launch(void* const* d_in, const int* in_sizes, int n_in,
                              void* d_out, int out_size, void* d_ws, size_t ws_size,
                              hipStream_t stream) {
    const float* x    = (const float*)d_in[0];
    const int*   ei   = (const int*)d_in[1];
    const int*   batch= (const int*)d_in[2];
    const float* W1   = (const float*)d_in[3];
    const float* b1   = (const float*)d_in[4];
    const float* W2   = (const float*)d_in[5];
    const float* b2   = (const float*)d_in[6];
    const float* W3   = (const float*)d_in[7];
    const float* b3   = (const float*)d_in[8];
    const float* Wl1  = (const float*)d_in[9];
    const float* bl1  = (const float*)d_in[10];
    const float* Wl2  = (const float*)d_in[11];
    const float* bl2  = (const float*)d_in[12];
    float* out = (float*)d_out;

    const int n  = in_sizes[2];      // 100000
    const int nE = in_sizes[1] / 2;  // 3200000
    const int* src = ei;
    const int* dst = ei + nE;

    char* w = (char*)d_ws;
    auto alloc_f = [&](size_t cnt) { float* p = (float*)w; w += cnt * 4; return p; };
    auto alloc_i = [&](size_t cnt) { int*   p = (int*)w;   w += cnt * 4; return p; };

    float* dinv   = alloc_f(n);
    int*   ideg   = alloc_i(n);
    int*   gcount = alloc_i(1);
    int*   start  = alloc_i(n);
    int*   cursor = alloc_i(n);
    int*   col    = alloc_i(nE);
    float* val    = alloc_f(nE);
    // region1: bufA(16n) h1(16n) h2(32n); h3(64n) aliases the whole region1
    float* bufA   = alloc_f((size_t)n * 16);
    float* h1     = alloc_f((size_t)n * 16);
    float* h2     = alloc_f((size_t)n * 32);
    float* h3     = bufA;              // aliases bufA..h2 (all dead by mm3)
    float* a2     = alloc_f((size_t)n * 32);
    float* pooled = alloc_f(1024 * 64);
    float* gcnt   = alloc_f(1024);

    const int B = 256;
    auto g = [&](long long t) { return (int)((t + B - 1) / B); };

    // ---- CSR build (once; reused by all 3 layers)
    k_fill_i<<<g(n + 1), B, 0, stream>>>(ideg, 0, n + 1);  // ideg + gcount contiguous
    k_count_deg<<<g(nE), B, 0, stream>>>(dst, ideg, nE);
    k_alloc<<<g(n), B, 0, stream>>>(ideg, dinv, start, cursor, gcount, n);
    k_csr_fill<<<g(nE), B, 0, stream>>>(src, dst, dinv, cursor, col, val, nE);

    // ---- layer 1: tmp = x@W1 (128->16); h1 = relu(Agg(tmp)+b1)
    k_mm<128, 16, false><<<g((long long)n * 16), B, 0, stream>>>(x, W1, nullptr, bufA, n);
    k_agg<16, true><<<g((long long)n * 16), B, 0, stream>>>(bufA, start, ideg, col, val, dinv, b1, h1, n);

    // ---- layer 2: a1 = Agg(h1) @16; h2 = relu(a1@W2+b2) (16->32)
    k_agg<16, false><<<g((long long)n * 16), B, 0, stream>>>(h1, start, ideg, col, val, dinv, nullptr, bufA, n);
    k_mm<16, 32, true><<<g((long long)n * 32), B, 0, stream>>>(bufA, W2, b2, h2, n);

    // ---- layer 3: a2 = Agg(h2) @32; h3 = relu(a2@W3+b3) (32->64)
    k_agg<32, false><<<g((long long)n * 32), B, 0, stream>>>(h2, start, ideg, col, val, dinv, nullptr, a2, n);
    k_mm<32, 64, true><<<g((long long)n * 64), B, 0, stream>>>(a2, W3, b3, h3, n);

    // ---- global mean pool + MLP head
    k_fill_f<<<g(1024 * 64 + 1024), B, 0, stream>>>(pooled, 0.0f, 1024 * 64 + 1024);
    k_pool<<<g((long long)n * 64), B, 0, stream>>>(h3, batch, pooled, gcnt, n);
    k_head<<<1024, 64, 0, stream>>>(pooled, gcnt, Wl1, bl1, Wl2, bl2, out);
}

// Round 3
// 771.848 us; speedup vs baseline: 2.0998x; 1.1379x over previous
//
#include <hip/hip_runtime.h>

// GCN forward: 3x GCNConv (symmetric norm, self-loops) + mean-pool + MLP head.
// R3: col-only CSR (val eliminated via dinv row-prescale), float4 agg,
//     sorted-batch run-length pool.

__global__ void k_fill_f(float* __restrict__ p, float v, int n) {
    int i = blockIdx.x * blockDim.x + threadIdx.x;
    if (i < n) p[i] = v;
}

__global__ void k_fill_i(int* __restrict__ p, int v, int n) {
    int i = blockIdx.x * blockDim.x + threadIdx.x;
    if (i < n) p[i] = v;
}

__global__ void k_count_deg(const int* __restrict__ dst, int* __restrict__ ideg, int nE) {
    int e = blockIdx.x * blockDim.x + threadIdx.x;
    if (e < nE) atomicAdd(&ideg[dst[e]], 1);
}

// dinv = rsqrt(ideg+1) ; allocate a contiguous CSR slab per node
__global__ void k_alloc(const int* __restrict__ ideg, float* __restrict__ dinv,
                        int* __restrict__ start, int* __restrict__ cursor,
                        int* __restrict__ gcount, int n) {
    int i = blockIdx.x * blockDim.x + threadIdx.x;
    if (i < n) {
        dinv[i] = rsqrtf((float)(ideg[i] + 1));
        int st = atomicAdd(gcount, ideg[i]);
        start[i] = st;
        cursor[i] = st;
    }
}

// CSR fill: col[pos] = src  (indices only — no per-edge values)
__global__ void k_csr_fill(const int* __restrict__ src, const int* __restrict__ dst,
                           int* __restrict__ cursor, int* __restrict__ col, int nE) {
    int e = blockIdx.x * blockDim.x + threadIdx.x;
    if (e < nE) {
        int s = src[e], d = dst[e];
        int pos = atomicAdd(&cursor[d], 1);
        col[pos] = s;
    }
}

// Aggregation over dinv-prescaled rows T (Td[s] = dinv[s]*P[s]):
//   total = T[i] + sum_e T[col[e]]
//   EPI 0: out = dinv[i]*total                      (plain Agg, feeds a matmul)
//   EPI 1: out = dinv[i]*relu(dinv[i]*total + b)    (layer-1: bias+relu, then
//                                                    pre-scale for next agg)
template <int F, int EPI>
__global__ void k_agg(const float* __restrict__ T, const int* __restrict__ start,
                      const int* __restrict__ cnt, const int* __restrict__ col,
                      const float* __restrict__ dinv, const float* __restrict__ bias,
                      float* __restrict__ out, int n) {
    constexpr int TPN = F / 4;  // float4 slots per node
    int idx = blockIdx.x * blockDim.x + threadIdx.x;
    int i = idx / TPN;
    int q = idx % TPN;
    if (i >= n) return;
    const float4* T4 = (const float4*)T;
    int base = start[i], c = cnt[i];
    float4 acc = T4[(size_t)i * TPN + q];  // self term
    int k = 0;
    for (; k + 4 <= c; k += 4) {
        int s0 = col[base + k],     s1 = col[base + k + 1];
        int s2 = col[base + k + 2], s3 = col[base + k + 3];
        float4 v0 = T4[(size_t)s0 * TPN + q];
        float4 v1 = T4[(size_t)s1 * TPN + q];
        float4 v2 = T4[(size_t)s2 * TPN + q];
        float4 v3 = T4[(size_t)s3 * TPN + q];
        acc.x += v0.x + v1.x + v2.x + v3.x;
        acc.y += v0.y + v1.y + v2.y + v3.y;
        acc.z += v0.z + v1.z + v2.z + v3.z;
        acc.w += v0.w + v1.w + v2.w + v3.w;
    }
    for (; k < c; ++k) {
        float4 v = T4[(size_t)col[base + k] * TPN + q];
        acc.x += v.x; acc.y += v.y; acc.z += v.z; acc.w += v.w;
    }
    float d = dinv[i];
    float4 o;
    if (EPI == 0) {
        o.x = d * acc.x; o.y = d * acc.y; o.z = d * acc.z; o.w = d * acc.w;
    } else {
        float4 b = ((const float4*)bias)[q];
        o.x = d * fmaxf(d * acc.x + b.x, 0.0f);
        o.y = d * fmaxf(d * acc.y + b.y, 0.0f);
        o.z = d * fmaxf(d * acc.z + b.z, 0.0f);
        o.w = d * fmaxf(d * acc.w + b.w, 0.0f);
    }
    ((float4*)out)[(size_t)i * TPN + q] = o;
}

// out[i][f] = epilogue( sum_k H[i][k]*W[k][f] )
//   EPI 0: out = dinv[i]*mm          (pre-scale for following agg)
//   EPI 1: out = dinv[i]*relu(mm+b)  (bias+relu, then pre-scale)
//   EPI 2: out = relu(mm+b)          (final feature layer)
template <int K, int F, int EPI>
__global__ void k_mm(const float* __restrict__ H, const float* __restrict__ W,
                     const float* __restrict__ b, const float* __restrict__ dinv,
                     float* __restrict__ out, int n) {
    __shared__ float sW[K * F];
    for (int t = threadIdx.x; t < K * F; t += blockDim.x) sW[t] = W[t];
    __syncthreads();
    int idx = blockIdx.x * blockDim.x + threadIdx.x;
    int i = idx / F, f = idx % F;
    if (i >= n) return;
    const float* h = H + (size_t)i * K;
    float acc = (EPI == 0) ? 0.0f : b[f];
    #pragma unroll 8
    for (int k = 0; k < K; ++k) acc += h[k] * sW[k * F + f];
    if (EPI != 0) acc = fmaxf(acc, 0.0f);
    if (EPI != 2) acc *= dinv[i];
    out[(size_t)i * F + f] = acc;
}

// batch is sorted: run-length accumulate, one atomic per (graph-run, feature).
__global__ void k_pool(const float* __restrict__ h3, const int* __restrict__ batch,
                       float* __restrict__ pooled, float* __restrict__ gcnt, int n) {
    const int CHUNK = 128;  // nodes per block
    int cs = blockIdx.x * CHUNK;
    int ce = min(cs + CHUNK, n);
    int f = threadIdx.x & 63;
    int r = threadIdx.x >> 6;  // 0..3
    int cur = -1;
    float acc = 0.0f, cn = 0.0f;
    for (int i = cs + r; i < ce; i += 4) {
        int g = batch[i];
        if (g != cur) {
            if (cur >= 0) {
                atomicAdd(&pooled[cur * 64 + f], acc);
                if (f == 0) atomicAdd(&gcnt[cur], cn);
            }
            cur = g; acc = 0.0f; cn = 0.0f;
        }
        acc += h3[(size_t)i * 64 + f];
        cn += 1.0f;
    }
    if (cur >= 0) {
        atomicAdd(&pooled[cur * 64 + f], acc);
        if (f == 0) atomicAdd(&gcnt[cur], cn);
    }
}

// one block (64 threads) per graph: mean -> relu(mean@Wl1+bl1) -> @Wl2+bl2
__global__ void k_head(const float* __restrict__ pooled, const float* __restrict__ gcnt,
                       const float* __restrict__ Wl1, const float* __restrict__ bl1,
                       const float* __restrict__ Wl2, const float* __restrict__ bl2,
                       float* __restrict__ out) {
    int g = blockIdx.x;
    int t = threadIdx.x;  // 0..63
    __shared__ float mean[64];
    __shared__ float hid[64];
    float c = fmaxf(gcnt[g], 1.0f);
    mean[t] = pooled[g * 64 + t] / c;
    __syncthreads();
    float acc = bl1[t];
    #pragma unroll 8
    for (int k = 0; k < 64; ++k) acc += mean[k] * Wl1[k * 64 + t];
    hid[t] = fmaxf(acc, 0.0f);
    __syncthreads();
    if (t < 2) {
        float o = bl2[t];
        #pragma unroll 8
        for (int k = 0; k < 64; ++k) o += hid[k] * Wl2[k * 2 + t];
        out[g * 2 + t] = o;
    }
}

extern "C" void kernel_launch(void* const* d_in, const int* in_sizes, int n_in,
                              void* d_out, int out_size, void* d_ws, size_t ws_size,
                              hipStream_t stream) {
    const float* x    = (const float*)d_in[0];
    const int*   ei   = (const int*)d_in[1];
    const int*   batch= (const int*)d_in[2];
    const float* W1   = (const float*)d_in[3];
    const float* b1   = (const float*)d_in[4];
    const float* W2   = (const float*)d_in[5];
    const float* b2   = (const float*)d_in[6];
    const float* W3   = (const float*)d_in[7];
    const float* b3   = (const float*)d_in[8];
    const float* Wl1  = (const float*)d_in[9];
    const float* bl1  = (const float*)d_in[10];
    const float* Wl2  = (const float*)d_in[11];
    const float* bl2  = (const float*)d_in[12];
    float* out = (float*)d_out;

    const int n  = in_sizes[2];      // 100000
    const int nE = in_sizes[1] / 2;  // 3200000
    const int* src = ei;
    const int* dst = ei + nE;

    char* w = (char*)d_ws;
    auto alloc_f = [&](size_t cnt) { float* p = (float*)w; w += cnt * 4; return p; };
    auto alloc_i = [&](size_t cnt) { int*   p = (int*)w;   w += cnt * 4; return p; };

    float* dinv   = alloc_f(n);
    int*   ideg   = alloc_i(n);
    int*   gcount = alloc_i(4);      // padded so later buffers stay 16B-aligned
    int*   start  = alloc_i(n);
    int*   cursor = alloc_i(n);
    int*   col    = alloc_i(nE);
    // feature region: Pd1(16n) h1d(16n) a1(16n) h2d(32n) — all dead by mm3;
    // h3(64n) aliases the region base.
    float* Pd1    = alloc_f((size_t)n * 16);
    float* h1d    = alloc_f((size_t)n * 16);
    float* a1     = alloc_f((size_t)n * 16);
    float* h2d    = alloc_f((size_t)n * 32);
    float* h3     = Pd1;
    float* a2     = alloc_f((size_t)n * 32);
    float* pooled = alloc_f(1024 * 64);
    float* gcnt   = alloc_f(1024);
    (void)h1d; (void)h2d;

    const int B = 256;
    auto g = [&](long long t) { return (int)((t + B - 1) / B); };

    // ---- CSR build (indices only; reused by all 3 layers)
    k_fill_i<<<g(n + 4), B, 0, stream>>>(ideg, 0, n + 4);  // ideg + gcount contiguous
    k_count_deg<<<g(nE), B, 0, stream>>>(dst, ideg, nE);
    k_alloc<<<g(n), B, 0, stream>>>(ideg, dinv, start, cursor, gcount, n);
    k_csr_fill<<<g(nE), B, 0, stream>>>(src, dst, cursor, col, nE);

    // ---- layer 1: Pd1 = dinv*(x@W1); h1d = dinv*relu(dinv*Agg(Pd1)+b1)
    k_mm<128, 16, 0><<<g((long long)n * 16), B, 0, stream>>>(x, W1, nullptr, dinv, Pd1, n);
    k_agg<16, 1><<<g((long long)n * 4), B, 0, stream>>>(Pd1, start, ideg, col, dinv, b1, h1d, n);

    // ---- layer 2: a1 = dinv*Agg(h1d); h2d = dinv*relu(a1@W2+b2)
    k_agg<16, 0><<<g((long long)n * 4), B, 0, stream>>>(h1d, start, ideg, col, dinv, nullptr, a1, n);
    k_mm<16, 32, 1><<<g((long long)n * 32), B, 0, stream>>>(a1, W2, b2, dinv, h2d, n);

    // ---- layer 3: a2 = dinv*Agg(h2d); h3 = relu(a2@W3+b3)
    k_agg<32, 0><<<g((long long)n * 8), B, 0, stream>>>(h2d, start, ideg, col, dinv, nullptr, a2, n);
    k_mm<32, 64, 2><<<g((long long)n * 64), B, 0, stream>>>(a2, W3, b3, dinv, h3, n);

    // ---- global mean pool + MLP head
    k_fill_f<<<g(1024 * 64 + 1024), B, 0, stream>>>(pooled, 0.0f, 1024 * 64 + 1024);
    k_pool<<<(n + 127) / 128, B, 0, stream>>>(h3, batch, pooled, gcnt, n);
    k_head<<<1024, 64, 0, stream>>>(pooled, gcnt, Wl1, bl1, Wl2, bl2, out);
}